// Round 1
// baseline (5027.440 us; speedup 1.0000x reference)
//
#include <hip/hip_runtime.h>
#include <string.h>

typedef _Float16 f16x8 __attribute__((ext_vector_type(8)));
typedef _Float16 f16x4 __attribute__((ext_vector_type(4)));
typedef float    f32x4 __attribute__((ext_vector_type(4)));

// Generic 2-level row addressing: addr(r) = (r>>sh)*hi + (r&msk)*lo   (in elements)
struct Addr { long hi; long lo; int sh; int msk; };

__device__ __forceinline__ long raddr(const Addr a, int r) {
  return ((long)(r >> a.sh)) * a.hi + ((long)(r & a.msk)) * a.lo;
}

struct GP {
  int M, N, K1, K2;
  const float* A1; Addr a1;    // K-segment 1 rows
  const float* A2; Addr a2;    // K-segment 2 rows (optional, K2>0)
  const float* B;  int ldb;    // B[k][n], rows 0..K1+K2
  const float* scale;          // optional: alpha *= *scale
  float alpha;
  const float* E1; Addr e1; float beta;   // C1 = alpha*acc + beta*E1
  float* C1; Addr c1;
  float* C2; Addr c2;          // C2 = alpha*acc + E2
  const float* E2; Addr e2;
  const float* fin;            // 256 partials: stage-scale = 1/sqrt(sum)
  float* fout;                 // per-block sum of squares of written values
};

// 64x64 tile, 4 waves (each 32x32 via 2x2 of mfma_f32_16x16x32_f16), BK=32.
// f32 in memory, f16 staged in LDS, f32 accumulate.
__global__ __launch_bounds__(256) void gemm_f16(GP p) {
  __shared__ _Float16 As[64 * 40];
  __shared__ _Float16 Bs[64 * 40];
  __shared__ float red[256];
  const int tid = threadIdx.x;
  const int nbn = (p.N + 63) >> 6;
  const int bm = blockIdx.x / nbn;
  const int bn = blockIdx.x - bm * nbn;
  const int m0 = bm << 6, n0 = bn << 6;

  float sscale = 1.0f;
  if (p.fin) {
    red[tid] = p.fin[tid];
    __syncthreads();
    for (int st = 128; st > 0; st >>= 1) {
      if (tid < st) red[tid] += red[tid + st];
      __syncthreads();
    }
    sscale = 1.0f / sqrtf(red[0]);
    __syncthreads();
  }
  float alpha = p.alpha;
  if (p.scale) alpha *= p.scale[0];

  const int w = tid >> 6;
  const int l = tid & 63;
  const int wm = w >> 1, wn = w & 1;
  const int lr = l & 15, lg = l >> 4;
  const int ar = tid >> 2, akq = tid & 3;     // A staging: row, k-quad
  const int bkr = tid >> 3, bnq = tid & 7;    // B staging: k-row, n-quad
  const bool rok = (m0 + ar) < p.M;

  f32x4 acc00 = {0.f,0.f,0.f,0.f}, acc01 = {0.f,0.f,0.f,0.f};
  f32x4 acc10 = {0.f,0.f,0.f,0.f}, acc11 = {0.f,0.f,0.f,0.f};
  const int Kt = p.K1 + p.K2;

  for (int k0 = 0; k0 < Kt; k0 += 32) {
    const float* Ab;
    Addr aa;
    long kl;
    if (k0 < p.K1) { Ab = p.A1; aa = p.a1; kl = k0; }
    else           { Ab = p.A2; aa = p.a2; kl = k0 - p.K1; }
    long rb = 0;
    if (rok) rb = raddr(aa, m0 + ar) + kl;
    #pragma unroll
    for (int s2 = 0; s2 < 2; ++s2) {
      const int kk = akq * 4 + s2 * 16;
      f32x4 v = {0.f,0.f,0.f,0.f};
      if (rok) v = *(const f32x4*)(Ab + rb + kk);
      f16x4 h;
      h[0] = (_Float16)(v[0] * sscale);
      h[1] = (_Float16)(v[1] * sscale);
      h[2] = (_Float16)(v[2] * sscale);
      h[3] = (_Float16)(v[3] * sscale);
      *(f16x4*)&As[ar * 40 + kk] = h;
    }
    #pragma unroll
    for (int s2 = 0; s2 < 2; ++s2) {
      const int nn = bnq * 4 + s2 * 32;
      f32x4 v = *(const f32x4*)(p.B + (long)(k0 + bkr) * p.ldb + n0 + nn);
      Bs[(nn + 0) * 40 + bkr] = (_Float16)(v[0] * sscale);
      Bs[(nn + 1) * 40 + bkr] = (_Float16)(v[1] * sscale);
      Bs[(nn + 2) * 40 + bkr] = (_Float16)(v[2] * sscale);
      Bs[(nn + 3) * 40 + bkr] = (_Float16)(v[3] * sscale);
    }
    __syncthreads();
    f16x8 fa0 = *(const f16x8*)&As[(wm * 32 +      lr) * 40 + lg * 8];
    f16x8 fa1 = *(const f16x8*)&As[(wm * 32 + 16 + lr) * 40 + lg * 8];
    f16x8 fb0 = *(const f16x8*)&Bs[(wn * 32 +      lr) * 40 + lg * 8];
    f16x8 fb1 = *(const f16x8*)&Bs[(wn * 32 + 16 + lr) * 40 + lg * 8];
    acc00 = __builtin_amdgcn_mfma_f32_16x16x32_f16(fa0, fb0, acc00, 0, 0, 0);
    acc01 = __builtin_amdgcn_mfma_f32_16x16x32_f16(fa0, fb1, acc01, 0, 0, 0);
    acc10 = __builtin_amdgcn_mfma_f32_16x16x32_f16(fa1, fb0, acc10, 0, 0, 0);
    acc11 = __builtin_amdgcn_mfma_f32_16x16x32_f16(fa1, fb1, acc11, 0, 0, 0);
    __syncthreads();
  }

  float ssq = 0.0f;
  #pragma unroll
  for (int i = 0; i < 2; ++i) {
    #pragma unroll
    for (int j = 0; j < 2; ++j) {
      f32x4 av = (i == 0) ? ((j == 0) ? acc00 : acc01)
                          : ((j == 0) ? acc10 : acc11);
      #pragma unroll
      for (int rr = 0; rr < 4; ++rr) {
        const int ro = m0 + wm * 32 + i * 16 + lg * 4 + rr;  // D row = (lane>>4)*4 + reg
        const int no = n0 + wn * 32 + j * 16 + lr;           // D col = lane&15
        if (ro < p.M) {
          float val = alpha * av[rr];
          if (p.C1) {
            float o1 = val;
            if (p.E1) o1 += p.beta * p.E1[raddr(p.e1, ro) + no];
            p.C1[raddr(p.c1, ro) + no] = o1;
          }
          if (p.C2) p.C2[raddr(p.c2, ro) + no] = val + p.E2[raddr(p.e2, ro) + no];
          ssq += val * val;
        }
      }
    }
  }
  if (p.fout) {
    __syncthreads();
    red[tid] = ssq;
    __syncthreads();
    for (int st = 128; st > 0; st >>= 1) {
      if (tid < st) red[tid] += red[tid + st];
      __syncthreads();
    }
    if (tid == 0) p.fout[blockIdx.x] = red[0];
  }
}

// out[i][j] = diag*(i==j) + sgn*mult*(*scale)*in[(roff+j)*ld + coff+i]
__global__ void tr_k(const float* in, long ld, long roff, long coff,
                     float* out, int n, const float* scale,
                     float mult, float diag, float sgn) {
  __shared__ float t[32][33];
  const int nb = n >> 5;
  const int bx = blockIdx.x % nb, by = blockIdx.x / nb;
  const long I0 = (long)bx * 32, J0 = (long)by * 32;
  const int tx = threadIdx.x, ty = threadIdx.y;
  #pragma unroll
  for (int k = 0; k < 4; ++k)
    t[ty * 4 + k][tx] = in[(roff + J0 + ty * 4 + k) * ld + coff + I0 + tx];
  __syncthreads();
  const float sc = scale ? scale[0] : 1.0f;
  const float f = sgn * mult * sc;
  #pragma unroll
  for (int k = 0; k < 4; ++k) {
    const long i = I0 + ty * 4 + k, j = J0 + tx;
    out[i * n + j] = ((i == j) ? diag : 0.0f) + f * t[tx][ty * 4 + k];
  }
}

__global__ void copy_rows_k(const float* src, Addr sa, float* dst, Addr da,
                            int M, int N4) {
  const long idx = (long)blockIdx.x * 256 + threadIdx.x;
  if (idx >= (long)M * N4) return;
  const int r = (int)(idx / N4);
  const long q = (idx - (long)r * N4) * 4;
  *(f32x4*)(dst + raddr(da, r) + q) = *(const f32x4*)(src + raddr(sa, r) + q);
}

// sigma from scale chain: ln l1(M0) = sum_{k<nsq} 2^-k ln s_k + 2^-nsq ln s_nsq
__global__ void scalar_k(const float* P, int nsq, const float* lg, float* sc) {
  if (threadIdx.x != 0 || blockIdx.x != 0) return;
  double lnl = 0.0, w = 1.0;
  for (int k = 0; k <= nsq; ++k) {
    double s = 0.0;
    for (int j = 0; j < 256; ++j) s += (double)P[k * 256 + j];
    double sk = sqrt(s);
    lnl += w * log(sk);
    if (k < nsq) w *= 0.5;
  }
  double sigma = exp(0.5 * lnl);
  if (sigma < 1e-5) sigma = 1e-5;
  const double invk = 1.0 / (sigma + 0.002);
  const double g = exp((double)lg[0]);
  sc[0] = (float)invk;        // invk
  sc[1] = (float)g;           // gamma
  sc[2] = (float)(g * invk);  // gamma*invk
}

static inline Addr lin(long stride) {
  Addr a; a.hi = 0; a.lo = stride; a.sh = 20; a.msk = 0xFFFFF; return a;
}
static inline Addr two(int sh, long hi, int msk, long lo) {
  Addr a; a.hi = hi; a.lo = lo; a.sh = sh; a.msk = msk; return a;
}
static inline GP gp0() {
  GP p; memset(&p, 0, sizeof(p)); p.alpha = 1.0f; p.beta = 1.0f; return p;
}

extern "C" void kernel_launch(void* const* d_in, const int* in_sizes, int n_in,
                              void* d_out, int out_size, void* d_ws, size_t ws_size,
                              hipStream_t stream) {
  (void)in_sizes; (void)n_in; (void)out_size; (void)ws_size;
  const float* u    = (const float*)d_in[0];  // [16][2048][512]
  const float* st0  = (const float*)d_in[1];  // [16][512]
  const float* S    = (const float*)d_in[2];  // [512][512]
  const float* Kr   = (const float*)d_in[3];  // [1024][1024]
  const float* lgam = (const float*)d_in[4];  // [1]

  float* outp   = (float*)d_out;                       // [16][2048][512]
  float* states = outp + (long)16 * 2048 * 512;        // [16][2049][512]
  float* ws = (float*)d_ws;

  const int NSQ = 12;
  float* sc = ws;                 // 3 scalars
  float* P  = ws + 64;            // (NSQ+1)*256 frobenius partials
  float* base = ws + 3456;

  // region1 (dead after scalar kernel)
  float* Krt = base;                  // 1024^2
  float* Ma  = base + 1048576;        // 1024^2
  float* Mb  = base + 2097152;        // 1024^2
  // region2 (overlaps region1; first written after region1 is dead)
  float* St   = base;                 // 512^2 each below
  float* Xa   = base + 262144;
  float* Xb   = base + 524288;
  float* Yn   = base + 786432;
  float* K11t = base + 1048576;
  float* K12t = base + 1310720;
  float* K21t = base + 1572864;
  float* W    = base + 1835008;
  float* ABst = base + 2097152;       // [At;Bt] 1024x512
  float* CtDt = base + 2621440;       // [Ct;Dt] 1024x512
  float* Qa   = base + 3145728;
  float* Qb   = base + 3407872;
  float* Yf   = base + 3670016;       // chunk-final y, 512x512
  float* Xall = base + 3932160;       // [16][33][512]
  float* Ha   = base + 4202496;
  float* Hb   = base + 4464640;

  auto launch = [&](const GP& p) {
    const int nbm = (p.M + 63) / 64, nbn = (p.N + 63) / 64;
    gemm_f16<<<dim3(nbm * nbn), dim3(256), 0, stream>>>(p);
  };

  // ---- Phase A: sigma via squaring chain ----
  tr_k<<<dim3(1024), dim3(32, 8), 0, stream>>>(Kr, 1024, 0, 0, Krt, 1024,
                                               nullptr, 1.f, 0.f, 1.f);
  {
    GP g = gp0();
    g.M = 1024; g.N = 1024; g.K1 = 1024;
    g.A1 = Krt; g.a1 = lin(1024);
    g.B = Kr; g.ldb = 1024;
    g.C1 = Ma; g.c1 = lin(1024);
    g.fout = P;
    launch(g);                 // M0 = Kr^T Kr, partials P0
  }
  {
    float* cur = Ma; float* nxt = Mb;
    for (int k = 1; k <= NSQ; ++k) {
      GP g = gp0();
      g.M = 1024; g.N = 1024; g.K1 = 1024;
      g.A1 = cur; g.a1 = lin(1024);
      g.B = cur; g.ldb = 1024;
      g.C1 = nxt; g.c1 = lin(1024);
      g.fin = P + (long)(k - 1) * 256;
      g.fout = P + (long)k * 256;
      launch(g);               // M_k = (M_{k-1}/s_{k-1})^2
      float* t = cur; cur = nxt; nxt = t;
    }
  }
  scalar_k<<<1, 64, 0, stream>>>(P, NSQ, lgam, sc);

  // ---- transposes / inits ----
  tr_k<<<dim3(256), dim3(32, 8), 0, stream>>>(S, 512, 0, 0, St, 512,
                                              nullptr, 1.f, 0.f, 1.f);     // St = S^T
  tr_k<<<dim3(256), dim3(32, 8), 0, stream>>>(S, 512, 0, 0, Xa, 512,
                                              nullptr, 1.f, 2.f, -1.f);    // X0 = 2I - S^T
  tr_k<<<dim3(256), dim3(32, 8), 0, stream>>>(Kr, 1024, 0, 0, K11t, 512,
                                              sc, 1.f, 0.f, 1.f);          // K11^T * invk
  tr_k<<<dim3(256), dim3(32, 8), 0, stream>>>(Kr, 1024, 0, 512, K12t, 512,
                                              sc, 1.f, 0.f, 1.f);          // K12^T * invk
  tr_k<<<dim3(256), dim3(32, 8), 0, stream>>>(Kr, 1024, 512, 0, K21t, 512,
                                              sc, 1.f, 0.f, 1.f);          // K21^T * invk
  tr_k<<<dim3(256), dim3(32, 8), 0, stream>>>(Kr, 1024, 512, 512, CtDt + 262144,
                                              512, sc + 2, 1.f, 0.f, 1.f); // Dt = g*invk*K22^T

  // ---- Newton: SinvT = (S^T)^-1, 4 iterations -> Xa ----
  for (int k = 0; k < 4; ++k) {
    float* cur = (k % 2 == 0) ? Xa : Xb;
    float* nxt = (k % 2 == 0) ? Xb : Xa;
    GP g = gp0();
    g.M = 512; g.N = 512; g.K1 = 512;
    g.A1 = St; g.a1 = lin(512);
    g.B = cur; g.ldb = 512;
    g.C1 = Yn; g.c1 = lin(512);
    launch(g);                 // Yn = St @ X
    GP h = gp0();
    h.M = 512; h.N = 512; h.K1 = 512;
    h.A1 = cur; h.a1 = lin(512);
    h.B = Yn; h.ldb = 512;
    h.alpha = -1.0f;
    h.E1 = cur; h.e1 = lin(512); h.beta = 2.0f;
    h.C1 = nxt; h.c1 = lin(512);
    launch(h);                 // X' = 2X - X@Yn
  }

  // ---- At, Bt, Ct ----
  {
    GP g = gp0(); g.M = 512; g.N = 512; g.K1 = 512;
    g.A1 = K11t; g.a1 = lin(512); g.B = Xa; g.ldb = 512;
    g.C1 = W; g.c1 = lin(512);
    launch(g);                 // W = K11t @ SinvT
  }
  {
    GP g = gp0(); g.M = 512; g.N = 512; g.K1 = 512;
    g.A1 = St; g.a1 = lin(512); g.B = W; g.ldb = 512;
    g.C1 = ABst; g.c1 = lin(512);
    launch(g);                 // At = St @ W
  }
  {
    GP g = gp0(); g.M = 512; g.N = 512; g.K1 = 512;
    g.A1 = K12t; g.a1 = lin(512); g.B = Xa; g.ldb = 512;
    g.scale = sc + 1;          // * gamma
    g.C1 = ABst + 262144; g.c1 = lin(512);
    launch(g);                 // Bt = gamma * K12t @ SinvT
  }
  {
    GP g = gp0(); g.M = 512; g.N = 512; g.K1 = 512;
    g.A1 = St; g.a1 = lin(512); g.B = K21t; g.ldb = 512;
    g.C1 = CtDt; g.c1 = lin(512);
    launch(g);                 // Ct = St @ K21t
  }

  // ---- AtL = At^64 (6 squarings) -> Qb ----
  {
    const float* src = ABst;
    float* dst = Qa;
    for (int k = 0; k < 6; ++k) {
      GP g = gp0(); g.M = 512; g.N = 512; g.K1 = 512;
      g.A1 = src; g.a1 = lin(512); g.B = src; g.ldb = 512;
      g.C1 = dst; g.c1 = lin(512);
      launch(g);
      src = dst; dst = (dst == Qa) ? Qb : Qa;
    }
  }

  // Addressing constants
  const Addr A_uchunk  = two(5, 1048576, 31, 32768);   // u rows (b,c) at step offset
  const Addr A_schunk  = two(5, 1049088, 31, 32768);   // states[b][c*64 + slot]
  const Addr A_xallbc  = two(5, 16896, 31, 512);       // Xall[b][c]
  const Addr A_srow    = two(11, 1049088, 2047, 512);  // states[b][t]

  // Xall[:,0,:] = initial state
  copy_rows_k<<<dim3(8), dim3(256), 0, stream>>>(st0, lin(512), Xall, lin(16896),
                                                 16, 128);

  // ---- pass1: zero-init chunk recurrences, y into states slots 1..63, final into Yf
  for (int i = 0; i < 64; ++i) {
    GP g = gp0();
    g.M = 512; g.N = 512; g.ldb = 512;
    if (i == 0) {
      g.K1 = 512; g.A1 = u; g.a1 = A_uchunk;
      g.B = ABst + 262144;   // Bt only
    } else {
      g.K1 = 512; g.A1 = states + (long)i * 512; g.a1 = A_schunk;
      g.K2 = 512; g.A2 = u + (long)i * 512; g.a2 = A_uchunk;
      g.B = ABst;            // [At; Bt]
    }
    if (i == 63) { g.C1 = Yf; g.c1 = lin(512); }
    else { g.C1 = states + (long)(i + 1) * 512; g.c1 = A_schunk; }
    launch(g);
  }

  // ---- chunk-level scan: X_{c+1} = X_c @ At^64 + Y_c ----
  for (int c = 0; c < 32; ++c) {
    GP g = gp0();
    g.M = 16; g.N = 512; g.K1 = 512;
    g.A1 = Xall + (long)c * 512; g.a1 = lin(16896);
    g.B = Qb; g.ldb = 512;
    g.E1 = Yf + (long)c * 512; g.e1 = lin(16384); g.beta = 1.0f;
    g.C1 = Xall + (long)(c + 1) * 512; g.c1 = lin(16896);
    launch(g);
  }

  // states[b][c*64] = Xall[b][c];  states[b][2048] = Xall[b][32]
  copy_rows_k<<<dim3(256), dim3(256), 0, stream>>>(Xall, A_xallbc, states, A_schunk,
                                                   512, 128);
  copy_rows_k<<<dim3(8), dim3(256), 0, stream>>>(Xall + 32 * 512, lin(16896),
                                                 states + (long)2048 * 512,
                                                 lin(1049088), 16, 128);

  // ---- pass2: homogeneous chains, states[slot i+1] += h_{i+1} ----
  for (int i = 0; i < 63; ++i) {
    GP g = gp0();
    g.M = 512; g.N = 512; g.K1 = 512; g.ldb = 512;
    g.B = ABst;  // At
    if (i == 0) { g.A1 = Xall; g.a1 = A_xallbc; }
    else { g.A1 = (i % 2 == 1) ? Ha : Hb; g.a1 = lin(512); }
    g.C1 = (i % 2 == 0) ? Ha : Hb; g.c1 = lin(512);
    g.C2 = states + (long)(i + 1) * 512; g.c2 = A_schunk;
    g.E2 = states + (long)(i + 1) * 512; g.e2 = A_schunk;
    launch(g);
  }

  // ---- output = states[:, :T] @ Ct + u @ Dt ----
  {
    GP g = gp0();
    g.M = 32768; g.N = 512;
    g.K1 = 512; g.A1 = states; g.a1 = A_srow;
    g.K2 = 512; g.A2 = u; g.a2 = lin(512);
    g.B = CtDt; g.ldb = 512;
    g.C1 = outp; g.c1 = lin(512);
    launch(g);
  }
}

// Round 2
// 3895.820 us; speedup vs baseline: 1.2905x; 1.2905x over previous
//
#include <hip/hip_runtime.h>
#include <string.h>

typedef _Float16 f16x8 __attribute__((ext_vector_type(8)));
typedef _Float16 f16x4 __attribute__((ext_vector_type(4)));
typedef float    f32x4 __attribute__((ext_vector_type(4)));

// Generic 2-level row addressing: addr(r) = (r>>sh)*hi + (r&msk)*lo   (in elements)
struct Addr { long hi; long lo; int sh; int msk; };

__device__ __forceinline__ long raddr(const Addr a, int r) {
  return ((long)(r >> a.sh)) * a.hi + ((long)(r & a.msk)) * a.lo;
}

struct GP {
  int M, N, K1, K2;
  const float* A1; Addr a1;    // K-segment 1 rows
  const float* A2; Addr a2;    // K-segment 2 rows (optional, K2>0)
  const float* B;  int ldb;    // B[k][n], rows 0..K1+K2
  const float* scale;          // optional: alpha *= *scale
  float alpha;
  const float* E1; Addr e1; float beta;   // C1 = alpha*acc + beta*E1
  float* C1; Addr c1;
  float* C2; Addr c2;          // C2 = alpha*acc + E2
  const float* E2; Addr e2;
  const float* fin;            // 256 partials: stage-scale = 1/sqrt(sum)
  float* fout;                 // per-block sum of squares of written values
};

struct GPB { GP g[8]; };

// 64x64 tile, 4 waves (each 32x32 via 2x2 of mfma_f32_16x16x32_f16), BK=32.
// f32 in memory, f16 staged in LDS, f32 accumulate.
__device__ __forceinline__ void gemm_body(const GP& p) {
  __shared__ _Float16 As[64 * 40];
  __shared__ _Float16 Bs[64 * 40];
  __shared__ float red[256];
  const int tid = threadIdx.x;
  const int nbn = (p.N + 63) >> 6;
  const int nbm = (p.M + 63) >> 6;
  if ((int)blockIdx.x >= nbm * nbn) return;
  const int bm = blockIdx.x / nbn;
  const int bn = blockIdx.x - bm * nbn;
  const int m0 = bm << 6, n0 = bn << 6;

  float sscale = 1.0f;
  if (p.fin) {
    red[tid] = p.fin[tid];
    __syncthreads();
    for (int st = 128; st > 0; st >>= 1) {
      if (tid < st) red[tid] += red[tid + st];
      __syncthreads();
    }
    sscale = 1.0f / sqrtf(red[0]);
    __syncthreads();
  }
  float alpha = p.alpha;
  if (p.scale) alpha *= p.scale[0];

  const int w = tid >> 6;
  const int l = tid & 63;
  const int wm = w >> 1, wn = w & 1;
  const int lr = l & 15, lg = l >> 4;
  const int ar = tid >> 2, akq = tid & 3;     // A staging: row, k-quad
  const int bkr = tid >> 3, bnq = tid & 7;    // B staging: k-row, n-quad
  const bool rok = (m0 + ar) < p.M;

  f32x4 acc00 = {0.f,0.f,0.f,0.f}, acc01 = {0.f,0.f,0.f,0.f};
  f32x4 acc10 = {0.f,0.f,0.f,0.f}, acc11 = {0.f,0.f,0.f,0.f};
  const int Kt = p.K1 + p.K2;

  for (int k0 = 0; k0 < Kt; k0 += 32) {
    const float* Ab;
    Addr aa;
    long kl;
    if (k0 < p.K1) { Ab = p.A1; aa = p.a1; kl = k0; }
    else           { Ab = p.A2; aa = p.a2; kl = k0 - p.K1; }
    long rb = 0;
    if (rok) rb = raddr(aa, m0 + ar) + kl;
    #pragma unroll
    for (int s2 = 0; s2 < 2; ++s2) {
      const int kk = akq * 4 + s2 * 16;
      f32x4 v = {0.f,0.f,0.f,0.f};
      if (rok) v = *(const f32x4*)(Ab + rb + kk);
      f16x4 h;
      h[0] = (_Float16)(v[0] * sscale);
      h[1] = (_Float16)(v[1] * sscale);
      h[2] = (_Float16)(v[2] * sscale);
      h[3] = (_Float16)(v[3] * sscale);
      *(f16x4*)&As[ar * 40 + kk] = h;
    }
    #pragma unroll
    for (int s2 = 0; s2 < 2; ++s2) {
      const int nn = bnq * 4 + s2 * 32;
      f32x4 v = *(const f32x4*)(p.B + (long)(k0 + bkr) * p.ldb + n0 + nn);
      Bs[(nn + 0) * 40 + bkr] = (_Float16)(v[0] * sscale);
      Bs[(nn + 1) * 40 + bkr] = (_Float16)(v[1] * sscale);
      Bs[(nn + 2) * 40 + bkr] = (_Float16)(v[2] * sscale);
      Bs[(nn + 3) * 40 + bkr] = (_Float16)(v[3] * sscale);
    }
    __syncthreads();
    f16x8 fa0 = *(const f16x8*)&As[(wm * 32 +      lr) * 40 + lg * 8];
    f16x8 fa1 = *(const f16x8*)&As[(wm * 32 + 16 + lr) * 40 + lg * 8];
    f16x8 fb0 = *(const f16x8*)&Bs[(wn * 32 +      lr) * 40 + lg * 8];
    f16x8 fb1 = *(const f16x8*)&Bs[(wn * 32 + 16 + lr) * 40 + lg * 8];
    acc00 = __builtin_amdgcn_mfma_f32_16x16x32_f16(fa0, fb0, acc00, 0, 0, 0);
    acc01 = __builtin_amdgcn_mfma_f32_16x16x32_f16(fa0, fb1, acc01, 0, 0, 0);
    acc10 = __builtin_amdgcn_mfma_f32_16x16x32_f16(fa1, fb0, acc10, 0, 0, 0);
    acc11 = __builtin_amdgcn_mfma_f32_16x16x32_f16(fa1, fb1, acc11, 0, 0, 0);
    __syncthreads();
  }

  float ssq = 0.0f;
  #pragma unroll
  for (int i = 0; i < 2; ++i) {
    #pragma unroll
    for (int j = 0; j < 2; ++j) {
      f32x4 av = (i == 0) ? ((j == 0) ? acc00 : acc01)
                          : ((j == 0) ? acc10 : acc11);
      #pragma unroll
      for (int rr = 0; rr < 4; ++rr) {
        const int ro = m0 + wm * 32 + i * 16 + lg * 4 + rr;  // D row = (lane>>4)*4 + reg
        const int no = n0 + wn * 32 + j * 16 + lr;           // D col = lane&15
        if (ro < p.M) {
          float val = alpha * av[rr];
          if (p.C1) {
            float o1 = val;
            if (p.E1) o1 += p.beta * p.E1[raddr(p.e1, ro) + no];
            p.C1[raddr(p.c1, ro) + no] = o1;
          }
          if (p.C2) p.C2[raddr(p.c2, ro) + no] = val + p.E2[raddr(p.e2, ro) + no];
          ssq += val * val;
        }
      }
    }
  }
  if (p.fout) {
    __syncthreads();
    red[tid] = ssq;
    __syncthreads();
    for (int st = 128; st > 0; st >>= 1) {
      if (tid < st) red[tid] += red[tid + st];
      __syncthreads();
    }
    if (tid == 0) p.fout[blockIdx.x] = red[0];
  }
}

__global__ __launch_bounds__(256) void gemm_f16_b(GPB pb) {
  gemm_body(pb.g[blockIdx.y]);
}

// out[i][j] = diag*(i==j) + sgn*mult*(*scale)*in[(roff+j)*ld + coff+i]
__global__ void tr_k(const float* in, long ld, long roff, long coff,
                     float* out, int n, const float* scale,
                     float mult, float diag, float sgn) {
  __shared__ float t[32][33];
  const int nb = n >> 5;
  const int bx = blockIdx.x % nb, by = blockIdx.x / nb;
  const long I0 = (long)bx * 32, J0 = (long)by * 32;
  const int tx = threadIdx.x, ty = threadIdx.y;
  #pragma unroll
  for (int k = 0; k < 4; ++k)
    t[ty * 4 + k][tx] = in[(roff + J0 + ty * 4 + k) * ld + coff + I0 + tx];
  __syncthreads();
  const float sc = scale ? scale[0] : 1.0f;
  const float f = sgn * mult * sc;
  #pragma unroll
  for (int k = 0; k < 4; ++k) {
    const long i = I0 + ty * 4 + k, j = J0 + tx;
    out[i * n + j] = ((i == j) ? diag : 0.0f) + f * t[tx][ty * 4 + k];
  }
}

__global__ void copy_rows_k(const float* src, Addr sa, float* dst, Addr da,
                            int M, int N4) {
  const long idx = (long)blockIdx.x * 256 + threadIdx.x;
  if (idx >= (long)M * N4) return;
  const int r = (int)(idx / N4);
  const long q = (idx - (long)r * N4) * 4;
  *(f32x4*)(dst + raddr(da, r) + q) = *(const f32x4*)(src + raddr(sa, r) + q);
}

// sigma from scale chain: ln l1(M0) = sum_{k<nsq} 2^-k ln s_k + 2^-nsq ln s_nsq
__global__ void scalar_k(const float* P, int nsq, const float* lg, float* sc) {
  if (threadIdx.x != 0 || blockIdx.x != 0) return;
  double lnl = 0.0, w = 1.0;
  for (int k = 0; k <= nsq; ++k) {
    double s = 0.0;
    for (int j = 0; j < 256; ++j) s += (double)P[k * 256 + j];
    double sk = sqrt(s);
    lnl += w * log(sk);
    if (k < nsq) w *= 0.5;
  }
  double sigma = exp(0.5 * lnl);
  if (sigma < 1e-5) sigma = 1e-5;
  const double invk = 1.0 / (sigma + 0.002);
  const double g = exp((double)lg[0]);
  sc[0] = (float)invk;        // invk
  sc[1] = (float)g;           // gamma
  sc[2] = (float)(g * invk);  // gamma*invk
}

static inline Addr lin(long stride) {
  Addr a; a.hi = 0; a.lo = stride; a.sh = 20; a.msk = 0xFFFFF; return a;
}
static inline Addr two(int sh, long hi, int msk, long lo) {
  Addr a; a.hi = hi; a.lo = lo; a.sh = sh; a.msk = msk; return a;
}
static inline GP gp0() {
  GP p; memset(&p, 0, sizeof(p)); p.alpha = 1.0f; p.beta = 1.0f; return p;
}

extern "C" void kernel_launch(void* const* d_in, const int* in_sizes, int n_in,
                              void* d_out, int out_size, void* d_ws, size_t ws_size,
                              hipStream_t stream) {
  (void)in_sizes; (void)n_in; (void)out_size; (void)ws_size;
  const float* u    = (const float*)d_in[0];  // [16][2048][512]
  const float* st0  = (const float*)d_in[1];  // [16][512]
  const float* S    = (const float*)d_in[2];  // [512][512]
  const float* Kr   = (const float*)d_in[3];  // [1024][1024]
  const float* lgam = (const float*)d_in[4];  // [1]

  float* outp   = (float*)d_out;                       // [16][2048][512]
  float* states = outp + (long)16 * 2048 * 512;        // [16][2049][512]
  float* ws = (float*)d_ws;

  const int NSQ = 12;
  float* sc = ws;                 // 3 scalars
  float* P  = ws + 64;            // (NSQ+1)*256 frobenius partials
  float* base = ws + 3456;

  // region1 (dead after scalar kernel)
  float* Krt = base;                  // 1024^2
  float* Ma  = base + 1048576;        // 1024^2
  float* Mb  = base + 2097152;        // 1024^2
  // region2 (overlaps region1; first written after scalar_k)
  float* St   = base;                 // 512^2 each below
  float* Xa   = base + 262144;
  float* Xb   = base + 524288;
  float* Yn   = base + 786432;
  float* K11t = base + 1048576;
  float* K12t = base + 1310720;
  float* K21t = base + 1572864;
  float* W    = base + 1835008;
  float* ABst = base + 2097152;       // [At;Bt] 1024x512
  float* CtDt = base + 2621440;       // [Ct;Dt] 1024x512  -> ends 3145728

  // big scratch lives in the outp region of d_out (written only by final GEMM)
  float* Apow = outp;                       // APow[j]=Apow+(j-1)*262144, j=1..16
  float* QB   = outp + 4194304;             // 4608x512: [Q8 Q7 Q6 Q5 Q4 Q3 Q2 Q1 I]
  float* Y    = outp + 6553600;             // [16*128][512] chunk-final local states
  float* Xc   = outp + 7602176;             // [16][129][512] chunk-initial states

  auto launchb = [&](const GP* gs, int nb) {
    GPB pb;
    memset(&pb, 0, sizeof(pb));
    int mx = 0;
    for (int i = 0; i < nb; ++i) {
      pb.g[i] = gs[i];
      int b = ((gs[i].M + 63) / 64) * ((gs[i].N + 63) / 64);
      if (b > mx) mx = b;
    }
    gemm_f16_b<<<dim3(mx, nb), dim3(256), 0, stream>>>(pb);
  };
  auto launch1 = [&](const GP& g) { launchb(&g, 1); };

  // ---- Phase A: sigma via squaring chain ----
  tr_k<<<dim3(1024), dim3(32, 8), 0, stream>>>(Kr, 1024, 0, 0, Krt, 1024,
                                               nullptr, 1.f, 0.f, 1.f);
  {
    GP g = gp0();
    g.M = 1024; g.N = 1024; g.K1 = 1024;
    g.A1 = Krt; g.a1 = lin(1024);
    g.B = Kr; g.ldb = 1024;
    g.C1 = Ma; g.c1 = lin(1024);
    g.fout = P;
    launch1(g);                // M0 = Kr^T Kr, partials P0
  }
  {
    float* cur = Ma; float* nxt = Mb;
    for (int k = 1; k <= NSQ; ++k) {
      GP g = gp0();
      g.M = 1024; g.N = 1024; g.K1 = 1024;
      g.A1 = cur; g.a1 = lin(1024);
      g.B = cur; g.ldb = 1024;
      g.C1 = nxt; g.c1 = lin(1024);
      g.fin = P + (long)(k - 1) * 256;
      g.fout = P + (long)k * 256;
      launch1(g);              // M_k = (M_{k-1}/s_{k-1})^2
      float* t = cur; cur = nxt; nxt = t;
    }
  }
  scalar_k<<<1, 64, 0, stream>>>(P, NSQ, lgam, sc);

  // ---- transposes / inits (region2 overwrites region1 from here) ----
  tr_k<<<dim3(256), dim3(32, 8), 0, stream>>>(S, 512, 0, 0, St, 512,
                                              nullptr, 1.f, 0.f, 1.f);     // St = S^T
  tr_k<<<dim3(256), dim3(32, 8), 0, stream>>>(S, 512, 0, 0, Xa, 512,
                                              nullptr, 1.f, 2.f, -1.f);    // X0 = 2I - S^T
  tr_k<<<dim3(256), dim3(32, 8), 0, stream>>>(Kr, 1024, 0, 0, K11t, 512,
                                              sc, 1.f, 0.f, 1.f);          // K11^T * invk
  tr_k<<<dim3(256), dim3(32, 8), 0, stream>>>(Kr, 1024, 0, 512, K12t, 512,
                                              sc, 1.f, 0.f, 1.f);          // K12^T * invk
  tr_k<<<dim3(256), dim3(32, 8), 0, stream>>>(Kr, 1024, 512, 0, K21t, 512,
                                              sc, 1.f, 0.f, 1.f);          // K21^T * invk
  tr_k<<<dim3(256), dim3(32, 8), 0, stream>>>(Kr, 1024, 512, 512, CtDt + 262144,
                                              512, sc + 2, 1.f, 0.f, 1.f); // Dt = g*invk*K22^T

  // ---- Newton: SinvT = (S^T)^-1, 3 iterations -> Xb ----
  for (int k = 0; k < 3; ++k) {
    float* cur = (k % 2 == 0) ? Xa : Xb;
    float* nxt = (k % 2 == 0) ? Xb : Xa;
    GP g = gp0();
    g.M = 512; g.N = 512; g.K1 = 512;
    g.A1 = St; g.a1 = lin(512);
    g.B = cur; g.ldb = 512;
    g.C1 = Yn; g.c1 = lin(512);
    launch1(g);                // Yn = St @ X
    GP h = gp0();
    h.M = 512; h.N = 512; h.K1 = 512;
    h.A1 = cur; h.a1 = lin(512);
    h.B = Yn; h.ldb = 512;
    h.alpha = -1.0f;
    h.E1 = cur; h.e1 = lin(512); h.beta = 2.0f;
    h.C1 = nxt; h.c1 = lin(512);
    launch1(h);                // X' = 2X - X@Yn
  }
  float* SinvT = Xb;

  // ---- {W, Ct} then {At, Bt} ----
  {
    GP gs[2];
    gs[0] = gp0();
    gs[0].M = 512; gs[0].N = 512; gs[0].K1 = 512;
    gs[0].A1 = K11t; gs[0].a1 = lin(512); gs[0].B = SinvT; gs[0].ldb = 512;
    gs[0].C1 = W; gs[0].c1 = lin(512);                      // W = K11t @ SinvT
    gs[1] = gp0();
    gs[1].M = 512; gs[1].N = 512; gs[1].K1 = 512;
    gs[1].A1 = St; gs[1].a1 = lin(512); gs[1].B = K21t; gs[1].ldb = 512;
    gs[1].C1 = CtDt; gs[1].c1 = lin(512);                   // Ct = St @ K21t
    launchb(gs, 2);
  }
  {
    GP gs[2];
    gs[0] = gp0();
    gs[0].M = 512; gs[0].N = 512; gs[0].K1 = 512;
    gs[0].A1 = St; gs[0].a1 = lin(512); gs[0].B = W; gs[0].ldb = 512;
    gs[0].C1 = ABst; gs[0].c1 = lin(512);                   // At = St @ W
    gs[1] = gp0();
    gs[1].M = 512; gs[1].N = 512; gs[1].K1 = 512;
    gs[1].A1 = K12t; gs[1].a1 = lin(512); gs[1].B = SinvT; gs[1].ldb = 512;
    gs[1].scale = sc + 1;
    gs[1].C1 = ABst + 262144; gs[1].c1 = lin(512);          // Bt = gamma*K12t@SinvT
    launchb(gs, 2);
  }

  // ---- At powers j=1..16 via doubling ----
  auto mm = [&](const float* A, const float* B, float* C) {
    GP g = gp0(); g.M = 512; g.N = 512; g.K1 = 512;
    g.A1 = A; g.a1 = lin(512); g.B = B; g.ldb = 512;
    g.C1 = C; g.c1 = lin(512);
    return g;
  };
  auto AP = [&](int j) { return Apow + (long)(j - 1) * 262144; };
  copy_rows_k<<<dim3(256), dim3(256), 0, stream>>>(ABst, lin(512), AP(1), lin(512),
                                                   512, 128);
  { GP g = mm(AP(1), AP(1), AP(2)); launch1(g); }
  { GP gs[2] = { mm(AP(2), AP(1), AP(3)), mm(AP(2), AP(2), AP(4)) };
    launchb(gs, 2); }
  { GP gs[4]; for (int i = 1; i <= 4; ++i) gs[i-1] = mm(AP(4), AP(i), AP(4+i));
    launchb(gs, 4); }
  { GP gs[8]; for (int i = 1; i <= 8; ++i) gs[i-1] = mm(AP(8), AP(i), AP(8+i));
    launchb(gs, 8); }

  // ---- Q powers into QB: blocks [Q8 Q7 Q6 Q5 Q4 Q3 Q2 Q1 I], Q = At^16 ----
  auto QBb = [&](int blk) { return QB + (long)blk * 262144; };
  copy_rows_k<<<dim3(256), dim3(256), 0, stream>>>(AP(16), lin(512), QBb(7), lin(512),
                                                   512, 128);               // Q^1
  tr_k<<<dim3(256), dim3(32, 8), 0, stream>>>(Kr, 1024, 0, 0, QBb(8), 512,
                                              nullptr, 0.f, 1.f, 1.f);      // I
  { GP g = mm(AP(16), AP(16), QBb(6)); launch1(g); }                        // Q^2
  { GP gs[2] = { mm(QBb(6), AP(16), QBb(5)), mm(QBb(6), QBb(6), QBb(4)) };
    launchb(gs, 2); }                                                       // Q^3,Q^4
  { GP gs[4] = { mm(QBb(4), AP(16), QBb(3)), mm(QBb(4), QBb(6), QBb(2)),
                 mm(QBb(4), QBb(5), QBb(1)), mm(QBb(4), QBb(4), QBb(0)) };
    launchb(gs, 4); }                                                       // Q^5..Q^8

  // Addressing constants (L=16, C=128 chunks/batch, row r=(b<<7)|c)
  const Addr A_u16  = two(7, 1048576, 127, 8192);
  const Addr A_s16  = two(7, 1049088, 127, 8192);
  const Addr A_xc   = two(7, 66048, 127, 512);
  const Addr A_srow = two(11, 1049088, 2047, 512);

  // Xc[:,0,:] = initial state
  copy_rows_k<<<dim3(8), dim3(256), 0, stream>>>(st0, lin(512), Xc, lin(66048),
                                                 16, 128);

  // ---- pass1: local zero-init scans, l_j -> states slots, l_16 -> Y ----
  for (int j = 1; j <= 16; ++j) {
    GP g = gp0();
    g.M = 2048; g.N = 512; g.ldb = 512;
    if (j == 1) {
      g.K1 = 512; g.A1 = u; g.a1 = A_u16;
      g.B = ABst + 262144;   // Bt only
    } else {
      g.K1 = 512; g.A1 = states + (long)(j - 1) * 512; g.a1 = A_s16;
      g.K2 = 512; g.A2 = u + (long)(j - 1) * 512; g.a2 = A_u16;
      g.B = ABst;            // [At; Bt]
    }
    if (j == 16) { g.C1 = Y; g.c1 = lin(512); }
    else { g.C1 = states + (long)j * 512; g.c1 = A_s16; }
    launch1(g);
  }

  // ---- coarse chunk scan (r=8 fused): X_{8(s+1)} = X_{8s} Q^8 + sum Y Q^{7-i}
  for (int s = 0; s < 16; ++s) {
    GP g = gp0();
    g.M = 16; g.N = 512;
    g.K1 = 512; g.A1 = Xc + (long)(8 * s) * 512; g.a1 = lin(66048);
    g.K2 = 4096; g.A2 = Y + (long)(8 * s) * 512; g.a2 = lin(65536);
    g.B = QB; g.ldb = 512;
    g.C1 = Xc + (long)(8 * s + 8) * 512; g.c1 = lin(66048);
    launch1(g);
  }

  // ---- chunk fill i=1..7 (batched): X_{8s+i} = X_{8s} Q^i + sum_{j<i} Y Q^{i-1-j}
  {
    GP gs[7];
    for (int i = 1; i <= 7; ++i) {
      GP g = gp0();
      g.M = 256; g.N = 512;
      g.K1 = 512; g.A1 = Xc; g.a1 = two(4, 66048, 15, 4096);
      g.K2 = 512 * i; g.A2 = Y; g.a2 = two(4, 65536, 15, 4096);
      g.B = QBb(8 - i); g.ldb = 512;
      g.C1 = Xc + (long)i * 512; g.c1 = two(4, 66048, 15, 4096);
      gs[i - 1] = g;
    }
    launchb(gs, 7);
  }

  // states[b][c*16] = Xc[b][c];  states[b][2048] = Xc[b][128]
  copy_rows_k<<<dim3(1024), dim3(256), 0, stream>>>(Xc, A_xc, states, A_s16,
                                                    2048, 128);
  copy_rows_k<<<dim3(8), dim3(256), 0, stream>>>(Xc + (long)128 * 512, lin(66048),
                                                 states + (long)2048 * 512,
                                                 lin(1049088), 16, 128);

  // ---- correction (batched): states[b, c*16+j] += Xc[b,c] @ At^j, j=1..15 ----
  {
    GP gs[8];
    for (int j = 1; j <= 8; ++j) {
      GP g = gp0();
      g.M = 2048; g.N = 512; g.K1 = 512;
      g.A1 = Xc; g.a1 = A_xc;
      g.B = AP(j); g.ldb = 512;
      g.C2 = states + (long)j * 512; g.c2 = A_s16;
      g.E2 = states + (long)j * 512; g.e2 = A_s16;
      gs[j - 1] = g;
    }
    launchb(gs, 8);
    for (int j = 9; j <= 15; ++j) {
      GP g = gp0();
      g.M = 2048; g.N = 512; g.K1 = 512;
      g.A1 = Xc; g.a1 = A_xc;
      g.B = AP(j); g.ldb = 512;
      g.C2 = states + (long)j * 512; g.c2 = A_s16;
      g.E2 = states + (long)j * 512; g.e2 = A_s16;
      gs[j - 9] = g;
    }
    launchb(gs, 7);
  }

  // ---- output = states[:, :T] @ Ct + u @ Dt ----
  {
    GP g = gp0();
    g.M = 32768; g.N = 512;
    g.K1 = 512; g.A1 = states; g.a1 = A_srow;
    g.K2 = 512; g.A2 = u; g.a2 = lin(512);
    g.B = CtDt; g.ldb = 512;
    g.C1 = outp; g.c1 = lin(512);
    launch1(g);
  }
}

// Round 3
// 1619.745 us; speedup vs baseline: 3.1038x; 2.4052x over previous
//
#include <hip/hip_runtime.h>
#include <string.h>

typedef _Float16 f16x8 __attribute__((ext_vector_type(8)));
typedef _Float16 f16x4 __attribute__((ext_vector_type(4)));
typedef float    f32x4 __attribute__((ext_vector_type(4)));

// Generic 2-level row addressing: addr(r) = (r>>sh)*hi + (r&msk)*lo   (in elements)
struct Addr { long hi; long lo; int sh; int msk; };

__device__ __forceinline__ long raddr(const Addr a, int r) {
  return ((long)(r >> a.sh)) * a.hi + ((long)(r & a.msk)) * a.lo;
}

struct GP {
  int M, N, K1, K2;
  const float* A1; Addr a1;    // K-segment 1 rows
  const float* A2; Addr a2;    // K-segment 2 rows (optional, K2>0)
  const float* B;  int ldb;    // B[k][n], rows 0..K1+K2
  const float* scale;          // optional: alpha *= *scale
  float alpha;
  const float* E1; Addr e1; float beta;   // C1 = alpha*acc + beta*E1
  float* C1; Addr c1;
  float* C2; Addr c2;          // C2 = alpha*acc + E2
  const float* E2; Addr e2;
  const float* fin;            // 256 partials: stage-scale = 1/sqrt(sum)
  float* fout;                 // per-block sum of squares of written values
};

struct GPB { GP g[8]; };

// Tiled GEMM, f32 memory / f16 LDS / f32 accum. 4 waves (2x2), wave-tile BM/2 x BN/2.
// Ping-pong LDS double-buffer; register-staged prefetch hides global latency.
// Requires (K1+K2) % 64 == 0, N % BN == 0.
template<int BM, int BN>
__device__ __forceinline__ void gemm_body(const GP& p) {
  constexpr int WTM = BM / 2, WTN = BN / 2;
  constexpr int FM = WTM / 16, FN = WTN / 16;
  constexpr int NAQ = BM / 32, NBQ = BN / 32;
  constexpr int BN4S = (BN == 64) ? 4 : 5;   // log2(BN/4)
  constexpr int BN4M = (BN / 4) - 1;
  __shared__ _Float16 As[2 * BM * 40];
  __shared__ _Float16 Bs[2 * BN * 40];
  __shared__ float red[256];
  const int tid = threadIdx.x;
  const int nbn = (p.N + BN - 1) / BN;
  const int nbm = (p.M + BM - 1) / BM;
  if ((int)blockIdx.x >= nbm * nbn) return;
  int bm, bn;
  {
    const int bid = blockIdx.x;
    if ((nbm & 7) == 0) {   // stripe-XCD swizzle: all bn of a stripe -> same XCD
      bm = (bid & 7) + ((bid >> 3) / nbn) * 8;
      bn = (bid >> 3) % nbn;
    } else {
      bm = bid / nbn; bn = bid - bm * nbn;
    }
  }
  const int m0 = bm * BM, n0 = bn * BN;

  float sscale = 1.0f;
  if (p.fin) {
    red[tid] = p.fin[tid];
    __syncthreads();
    for (int st = 128; st > 0; st >>= 1) {
      if (tid < st) red[tid] += red[tid + st];
      __syncthreads();
    }
    sscale = 1.0f / sqrtf(red[0]);
    __syncthreads();
  }
  float alpha = p.alpha;
  if (p.scale) alpha *= p.scale[0];

  const int w = tid >> 6, l = tid & 63;
  const int wm = w >> 1, wn = w & 1;
  const int lr = l & 15, lg = l >> 4;

  f32x4 acc[FM][FN];
  #pragma unroll
  for (int m = 0; m < FM; ++m)
    #pragma unroll
    for (int n = 0; n < FN; ++n) acc[m][n] = {0.f, 0.f, 0.f, 0.f};

  const int Kt = p.K1 + p.K2;

  f32x4 aR0[NAQ], bR0[NBQ], aR1[NAQ], bR1[NBQ];

  auto loadT = [&](int k0, f32x4* aR, f32x4* bR) {
    const float* Ab; Addr aa; long kl;
    if (k0 < p.K1) { Ab = p.A1; aa = p.a1; kl = k0; }
    else           { Ab = p.A2; aa = p.a2; kl = (long)k0 - p.K1; }
    #pragma unroll
    for (int i = 0; i < NAQ; ++i) {
      const int gq = tid + (i << 8);
      const int ar_ = gq >> 3, kq = gq & 7;
      f32x4 v = {0.f, 0.f, 0.f, 0.f};
      if (m0 + ar_ < p.M) v = *(const f32x4*)(Ab + raddr(aa, m0 + ar_) + kl + kq * 4);
      aR[i] = v;
    }
    #pragma unroll
    for (int i = 0; i < NBQ; ++i) {
      const int gq = tid + (i << 8);
      const int bk_ = gq >> BN4S, bq = gq & BN4M;
      bR[i] = *(const f32x4*)(p.B + (long)(k0 + bk_) * p.ldb + n0 + bq * 4);
    }
  };
  auto storeLDS = [&](int buf, const f32x4* aR, const f32x4* bR) {
    #pragma unroll
    for (int i = 0; i < NAQ; ++i) {
      const int gq = tid + (i << 8);
      const int ar_ = gq >> 3, kq = gq & 7;
      f16x4 h;
      h[0] = (_Float16)(aR[i][0] * sscale);
      h[1] = (_Float16)(aR[i][1] * sscale);
      h[2] = (_Float16)(aR[i][2] * sscale);
      h[3] = (_Float16)(aR[i][3] * sscale);
      *(f16x4*)&As[buf * BM * 40 + ar_ * 40 + kq * 4] = h;
    }
    #pragma unroll
    for (int i = 0; i < NBQ; ++i) {
      const int gq = tid + (i << 8);
      const int bk_ = gq >> BN4S, bq = gq & BN4M;
      _Float16* bb = &Bs[buf * BN * 40];
      bb[(bq * 4 + 0) * 40 + bk_] = (_Float16)(bR[i][0] * sscale);
      bb[(bq * 4 + 1) * 40 + bk_] = (_Float16)(bR[i][1] * sscale);
      bb[(bq * 4 + 2) * 40 + bk_] = (_Float16)(bR[i][2] * sscale);
      bb[(bq * 4 + 3) * 40 + bk_] = (_Float16)(bR[i][3] * sscale);
    }
  };
  auto compute = [&](int buf) {
    f16x8 a[FM], b[FN];
    #pragma unroll
    for (int m = 0; m < FM; ++m)
      a[m] = *(const f16x8*)&As[buf * BM * 40 + (wm * WTM + m * 16 + lr) * 40 + lg * 8];
    #pragma unroll
    for (int n = 0; n < FN; ++n)
      b[n] = *(const f16x8*)&Bs[buf * BN * 40 + (wn * WTN + n * 16 + lr) * 40 + lg * 8];
    #pragma unroll
    for (int m = 0; m < FM; ++m)
      #pragma unroll
      for (int n = 0; n < FN; ++n)
        acc[m][n] = __builtin_amdgcn_mfma_f32_16x16x32_f16(a[m], b[n], acc[m][n], 0, 0, 0);
  };

  loadT(0, aR0, bR0);
  for (int k0 = 0; k0 < Kt; k0 += 64) {
    storeLDS(0, aR0, bR0);
    loadT(k0 + 32, aR1, bR1);
    __syncthreads();
    compute(0);
    storeLDS(1, aR1, bR1);
    if (k0 + 64 < Kt) loadT(k0 + 64, aR0, bR0);
    __syncthreads();
    compute(1);
  }

  float ssq = 0.0f;
  #pragma unroll
  for (int m = 0; m < FM; ++m) {
    #pragma unroll
    for (int n = 0; n < FN; ++n) {
      #pragma unroll
      for (int rr = 0; rr < 4; ++rr) {
        const int ro = m0 + wm * WTM + m * 16 + lg * 4 + rr;
        const int no = n0 + wn * WTN + n * 16 + lr;
        if (ro < p.M) {
          float val = alpha * acc[m][n][rr];
          if (p.C1) {
            float o1 = val;
            if (p.E1) o1 += p.beta * p.E1[raddr(p.e1, ro) + no];
            p.C1[raddr(p.c1, ro) + no] = o1;
          }
          if (p.C2) p.C2[raddr(p.c2, ro) + no] = val + p.E2[raddr(p.e2, ro) + no];
          ssq += val * val;
        }
      }
    }
  }
  if (p.fout) {
    __syncthreads();
    red[tid] = ssq;
    __syncthreads();
    for (int st = 128; st > 0; st >>= 1) {
      if (tid < st) red[tid] += red[tid + st];
      __syncthreads();
    }
    if (tid == 0) p.fout[blockIdx.x] = red[0];
  }
}

__global__ __launch_bounds__(256) void gemm_S(GPB pb) { gemm_body<64, 64>(pb.g[blockIdx.y]); }
__global__ __launch_bounds__(256) void gemm_L(GPB pb) { gemm_body<128, 128>(pb.g[blockIdx.y]); }

// out[i][j] = diag*(i==j) + sgn*mult*(*scale)*in[(roff+j)*ld + coff+i]
__global__ void tr_k(const float* in, long ld, long roff, long coff,
                     float* out, int n, const float* scale,
                     float mult, float diag, float sgn) {
  __shared__ float t[32][33];
  const int nb = n >> 5;
  const int bx = blockIdx.x % nb, by = blockIdx.x / nb;
  const long I0 = (long)bx * 32, J0 = (long)by * 32;
  const int tx = threadIdx.x, ty = threadIdx.y;
  #pragma unroll
  for (int k = 0; k < 4; ++k)
    t[ty * 4 + k][tx] = in[(roff + J0 + ty * 4 + k) * ld + coff + I0 + tx];
  __syncthreads();
  const float sc = scale ? scale[0] : 1.0f;
  const float f = sgn * mult * sc;
  #pragma unroll
  for (int k = 0; k < 4; ++k) {
    const long i = I0 + ty * 4 + k, j = J0 + tx;
    out[i * n + j] = ((i == j) ? diag : 0.0f) + f * t[tx][ty * 4 + k];
  }
}

__global__ void copy_rows_k(const float* src, Addr sa, float* dst, Addr da,
                            int M, int N4) {
  const long idx = (long)blockIdx.x * 256 + threadIdx.x;
  if (idx >= (long)M * N4) return;
  const int r = (int)(idx / N4);
  const long q = (idx - (long)r * N4) * 4;
  *(f32x4*)(dst + raddr(da, r) + q) = *(const f32x4*)(src + raddr(sa, r) + q);
}

// sigma from scale chain: ln l1(M0) = sum_{k<nsq} 2^-k ln s_k + 2^-nsq ln s_nsq
__global__ void scalar_k(const float* P, int nsq, const float* lg, float* sc) {
  if (threadIdx.x != 0 || blockIdx.x != 0) return;
  double lnl = 0.0, w = 1.0;
  for (int k = 0; k <= nsq; ++k) {
    double s = 0.0;
    for (int j = 0; j < 256; ++j) s += (double)P[k * 256 + j];
    double sk = sqrt(s);
    lnl += w * log(sk);
    if (k < nsq) w *= 0.5;
  }
  double sigma = exp(0.5 * lnl);
  if (sigma < 1e-5) sigma = 1e-5;
  const double invk = 1.0 / (sigma + 0.002);
  const double g = exp((double)lg[0]);
  sc[0] = (float)invk;        // invk
  sc[1] = (float)g;           // gamma
  sc[2] = (float)(g * invk);  // gamma*invk
}

static inline Addr lin(long stride) {
  Addr a; a.hi = 0; a.lo = stride; a.sh = 20; a.msk = 0xFFFFF; return a;
}
static inline Addr two(int sh, long hi, int msk, long lo) {
  Addr a; a.hi = hi; a.lo = lo; a.sh = sh; a.msk = msk; return a;
}
static inline GP gp0() {
  GP p; memset(&p, 0, sizeof(p)); p.alpha = 1.0f; p.beta = 1.0f; return p;
}

extern "C" void kernel_launch(void* const* d_in, const int* in_sizes, int n_in,
                              void* d_out, int out_size, void* d_ws, size_t ws_size,
                              hipStream_t stream) {
  (void)in_sizes; (void)n_in; (void)out_size; (void)ws_size;
  const float* u    = (const float*)d_in[0];  // [16][2048][512]
  const float* st0  = (const float*)d_in[1];  // [16][512]
  const float* S    = (const float*)d_in[2];  // [512][512]
  const float* Kr   = (const float*)d_in[3];  // [1024][1024]
  const float* lgam = (const float*)d_in[4];  // [1]

  float* outp   = (float*)d_out;                       // [16][2048][512]
  float* states = outp + (long)16 * 2048 * 512;        // [16][2049][512]
  float* ws = (float*)d_ws;

  const int NSQ = 12;
  float* sc = ws;                 // 3 scalars
  float* P  = ws + 64;            // (NSQ+1)*256 frobenius partials
  float* base = ws + 3456;

  // region1 (dead after scalar kernel)
  float* Krt = base;                  // 1024^2
  float* Ma  = base + 1048576;        // 1024^2
  float* Mb  = base + 2097152;        // 1024^2
  // region2 (overlaps region1; first written after scalar_k)
  float* St   = base;                 // 512^2 each below
  float* Xa   = base + 262144;
  float* Xb   = base + 524288;
  float* Yn   = base + 786432;
  float* K11t = base + 1048576;
  float* K12t = base + 1310720;
  float* K21t = base + 1572864;
  float* W    = base + 1835008;
  float* ABst = base + 2097152;       // [At;Bt] 1024x512
  float* CtDt = base + 2621440;       // [Ct;Dt] 1024x512  -> ends 3145728

  // big scratch lives in the outp region of d_out (dead before final GEMM writes)
  float* Za  = outp;                  // [16][512][512] Kogge-Stone ping
  float* Zb  = outp + 4194304;        // [16][512][512] Kogge-Stone pong
  float* APb = outp + 8388608;        // At^j, j=2..8 : APb+(j-2)*262144
  float* Tb  = outp + 10223616;       // Q^(2^k), k=1..8 : Tb+(k-1)*262144

  auto launchSb = [&](const GP* gs, int nb) {
    GPB pb; memset(&pb, 0, sizeof(pb));
    int mx = 0;
    for (int i = 0; i < nb; ++i) {
      pb.g[i] = gs[i];
      int b = ((gs[i].M + 63) / 64) * ((gs[i].N + 63) / 64);
      if (b > mx) mx = b;
    }
    gemm_S<<<dim3(mx, nb), dim3(256), 0, stream>>>(pb);
  };
  auto launchS = [&](const GP& g) { launchSb(&g, 1); };
  auto launchLb = [&](const GP* gs, int nb) {
    GPB pb; memset(&pb, 0, sizeof(pb));
    int mx = 0;
    for (int i = 0; i < nb; ++i) {
      pb.g[i] = gs[i];
      int b = ((gs[i].M + 127) / 128) * ((gs[i].N + 127) / 128);
      if (b > mx) mx = b;
    }
    gemm_L<<<dim3(mx, nb), dim3(256), 0, stream>>>(pb);
  };
  auto launchL = [&](const GP& g) { launchLb(&g, 1); };

  auto mm = [&](const float* A, const float* B, float* C) {
    GP g = gp0(); g.M = 512; g.N = 512; g.K1 = 512;
    g.A1 = A; g.a1 = lin(512); g.B = B; g.ldb = 512;
    g.C1 = C; g.c1 = lin(512);
    return g;
  };

  // ---- Phase A: sigma via squaring chain ----
  tr_k<<<dim3(1024), dim3(32, 8), 0, stream>>>(Kr, 1024, 0, 0, Krt, 1024,
                                               nullptr, 1.f, 0.f, 1.f);
  {
    GP g = gp0();
    g.M = 1024; g.N = 1024; g.K1 = 1024;
    g.A1 = Krt; g.a1 = lin(1024);
    g.B = Kr; g.ldb = 1024;
    g.C1 = Ma; g.c1 = lin(1024);
    g.fout = P;
    launchS(g);                // M0 = Kr^T Kr, partials P0
  }
  {
    float* cur = Ma; float* nxt = Mb;
    for (int k = 1; k <= NSQ; ++k) {
      GP g = gp0();
      g.M = 1024; g.N = 1024; g.K1 = 1024;
      g.A1 = cur; g.a1 = lin(1024);
      g.B = cur; g.ldb = 1024;
      g.C1 = nxt; g.c1 = lin(1024);
      g.fin = P + (long)(k - 1) * 256;
      g.fout = P + (long)k * 256;
      launchS(g);              // M_k = (M_{k-1}/s_{k-1})^2
      float* t = cur; cur = nxt; nxt = t;
    }
  }
  scalar_k<<<1, 64, 0, stream>>>(P, NSQ, lgam, sc);

  // ---- transposes / inits (region2 overwrites region1 from here) ----
  tr_k<<<dim3(256), dim3(32, 8), 0, stream>>>(S, 512, 0, 0, St, 512,
                                              nullptr, 1.f, 0.f, 1.f);     // St = S^T
  tr_k<<<dim3(256), dim3(32, 8), 0, stream>>>(S, 512, 0, 0, Xa, 512,
                                              nullptr, 1.f, 2.f, -1.f);    // X0 = 2I - S^T
  tr_k<<<dim3(256), dim3(32, 8), 0, stream>>>(Kr, 1024, 0, 0, K11t, 512,
                                              sc, 1.f, 0.f, 1.f);          // K11^T * invk
  tr_k<<<dim3(256), dim3(32, 8), 0, stream>>>(Kr, 1024, 0, 512, K12t, 512,
                                              sc, 1.f, 0.f, 1.f);          // K12^T * invk
  tr_k<<<dim3(256), dim3(32, 8), 0, stream>>>(Kr, 1024, 512, 0, K21t, 512,
                                              sc, 1.f, 0.f, 1.f);          // K21^T * invk
  tr_k<<<dim3(256), dim3(32, 8), 0, stream>>>(Kr, 1024, 512, 512, CtDt + 262144,
                                              512, sc + 2, 1.f, 0.f, 1.f); // Dt = g*invk*K22^T

  // ---- Newton: SinvT = (S^T)^-1, 3 iterations -> Xb ----
  for (int k = 0; k < 3; ++k) {
    float* cur = (k % 2 == 0) ? Xa : Xb;
    float* nxt = (k % 2 == 0) ? Xb : Xa;
    GP g = gp0();
    g.M = 512; g.N = 512; g.K1 = 512;
    g.A1 = St; g.a1 = lin(512);
    g.B = cur; g.ldb = 512;
    g.C1 = Yn; g.c1 = lin(512);
    launchS(g);                // Yn = St @ X
    GP h = gp0();
    h.M = 512; h.N = 512; h.K1 = 512;
    h.A1 = cur; h.a1 = lin(512);
    h.B = Yn; h.ldb = 512;
    h.alpha = -1.0f;
    h.E1 = cur; h.e1 = lin(512); h.beta = 2.0f;
    h.C1 = nxt; h.c1 = lin(512);
    launchS(h);                // X' = 2X - X@Yn
  }
  float* SinvT = Xb;

  // ---- {W, Ct} then {At, Bt} ----
  {
    GP gs[2];
    gs[0] = mm(K11t, SinvT, W);                       // W = K11t @ SinvT
    gs[1] = mm(St, K21t, CtDt);                       // Ct = St @ K21t
    launchSb(gs, 2);
  }
  {
    GP gs[2];
    gs[0] = mm(St, W, ABst);                          // At = St @ W
    gs[1] = mm(K12t, SinvT, ABst + 262144);           // Bt = gamma*K12t@SinvT
    gs[1].scale = sc + 1;
    launchSb(gs, 2);
  }

  // ---- At powers j=2..8 via doubling (AP(1) aliases ABst) ----
  auto AP = [&](int j) -> float* {
    return (j == 1) ? ABst : APb + (long)(j - 2) * 262144;
  };
  { GP g = mm(AP(1), AP(1), AP(2)); launchS(g); }
  { GP gs[2] = { mm(AP(2), AP(1), AP(3)), mm(AP(2), AP(2), AP(4)) };
    launchSb(gs, 2); }
  { GP gs[4]; for (int i = 1; i <= 4; ++i) gs[i-1] = mm(AP(4), AP(i), AP(4+i));
    launchSb(gs, 4); }

  // ---- T(k) = Q^(2^k), Q = At^8 ; T(0)=AP(8), T(k)=T(k-1)^2 ----
  auto Tm = [&](int k) -> float* {
    return (k == 0) ? AP(8) : Tb + (long)(k - 1) * 262144;
  };
  for (int k = 1; k <= 8; ++k) { GP g = mm(Tm(k-1), Tm(k-1), Tm(k)); launchS(g); }

  // Addressing constants (L=8, 256 chunks/batch)
  const Addr A_u8   = two(8, 1048576, 255, 4096);   // u[b][8c] rows, r=(b<<8)|c
  const Addr A_s8   = two(8, 1049088, 255, 4096);   // states[b][8c] rows
  const Addr A_z    = two(8, 262144, 255, 512);     // Z[b][c] slots (512-slot pad)
  const Addr A_srow = two(11, 1049088, 2047, 512);  // states[b][t]

  // Z init: slot (b,0) = initial state; pass1 j=8 fills slots 1..256
  copy_rows_k<<<dim3(8), dim3(256), 0, stream>>>(st0, lin(512), Za, lin(262144),
                                                 16, 128);

  // ---- pass1: local zero-init scans; l_j -> states slot c*8+j (j=1..7), l_8 -> Za[c+1]
  for (int j = 1; j <= 8; ++j) {
    GP g = gp0();
    g.M = 4096; g.N = 512; g.ldb = 512;
    if (j == 1) {
      g.K1 = 512; g.A1 = u; g.a1 = A_u8;
      g.B = ABst + 262144;   // Bt only
    } else {
      g.K1 = 512; g.A1 = states + (long)(j - 1) * 512; g.a1 = A_s8;
      g.K2 = 512; g.A2 = u + (long)(j - 1) * 512; g.a2 = A_u8;
      g.B = ABst;            // [At; Bt]
    }
    if (j == 8) { g.C1 = Za + 512; g.c1 = A_z; }
    else { g.C1 = states + (long)j * 512; g.c1 = A_s8; }
    launchS(g);
  }

  // ---- Kogge-Stone weighted prefix over 257 chunk states ----
  // W_c <- W_c + W_{c-2^k} @ Q^(2^k), k=0..8; ping-pong Za/Zb (512-slot padded)
  for (int k = 0; k <= 8; ++k) {
    const int s = 1 << k;
    float* Zs = (k % 2 == 0) ? Za : Zb;
    float* Zd = (k % 2 == 0) ? Zb : Za;
    GP g = gp0();
    g.M = 4096; g.N = 512; g.K1 = 512;
    g.A1 = Zs; g.a1 = A_z;                       // W_{c-s}, rows (b, i=c-s)
    g.B = Tm(k); g.ldb = 512;
    g.E1 = Zs + (long)s * 512; g.e1 = A_z; g.beta = 1.0f;
    g.C1 = Zd + (long)s * 512; g.c1 = A_z;
    launchS(g);
    // carry over untouched slots c < s
    copy_rows_k<<<dim3(8 * s), dim3(256), 0, stream>>>(
        Zs, two(k, 262144, s - 1, 512), Zd, two(k, 262144, s - 1, 512),
        16 * s, 128);
  }
  float* Zf = Zb;   // 9 rounds: Za->Zb->...->Zb

  // states[b][c*8] = Zf[b][c];  states[b][2048] = Zf[b][256]
  copy_rows_k<<<dim3(2048), dim3(256), 0, stream>>>(Zf, A_z, states, A_s8,
                                                    4096, 128);
  copy_rows_k<<<dim3(8), dim3(256), 0, stream>>>(Zf + (long)256 * 512, lin(262144),
                                                 states + (long)2048 * 512,
                                                 lin(1049088), 16, 128);

  // ---- corrections (batched): states[b][c*8+j] += Zf[b][c] @ At^j, j=1..7 ----
  {
    GP gs[7];
    for (int j = 1; j <= 7; ++j) {
      GP g = gp0();
      g.M = 4096; g.N = 512; g.K1 = 512;
      g.A1 = Zf; g.a1 = A_z;
      g.B = AP(j); g.ldb = 512;
      g.C2 = states + (long)j * 512; g.c2 = A_s8;
      g.E2 = states + (long)j * 512; g.e2 = A_s8;
      gs[j - 1] = g;
    }
    launchLb(gs, 7);
  }

  // ---- output = states[:, :T] @ Ct + u @ Dt ----
  {
    GP g = gp0();
    g.M = 32768; g.N = 512;
    g.K1 = 512; g.A1 = states; g.a1 = A_srow;
    g.K2 = 512; g.A2 = u; g.a2 = lin(512);
    g.B = CtDt; g.ldb = 512;
    g.C1 = outp; g.c1 = lin(512);
    launchL(g);
  }
}